// Round 14
// baseline (72.890 us; speedup 1.0000x reference)
//
#include <hip/hip_runtime.h>

#define B_TOT 2048
#define NHEAD 3

typedef __attribute__((ext_vector_type(8))) short short8v;
typedef __attribute__((ext_vector_type(4))) float f32x4;
typedef __attribute__((ext_vector_type(2))) __fp16 f16x2;

#define LOG2E 1.4426950408889634f

static __device__ __forceinline__ unsigned short f2bf(float x) {
    unsigned u = __builtin_bit_cast(unsigned, x);
    u += 0x7FFFu + ((u >> 16) & 1u);
    return (unsigned short)(u >> 16);
}
static __device__ __forceinline__ float bf2f(unsigned short s) {
    unsigned u = ((unsigned)s) << 16;
    return __builtin_bit_cast(float, u);
}
static __device__ __forceinline__ float exp2_fast(float x) {
    float r; asm("v_exp_f32 %0, %1" : "=v"(r) : "v"(x)); return r;
}

// ---------------------------------------------------------------------------
// Bias MLP body (shared by standalone kernel and conv-kernel tail):
//   bias2[((h*16 + mt*4 + nt) * 64 + lane) * 4 + r], pre-scaled by log2e,
//   n = 16*mt + 4*(lane>>4) + r, m = 16*nt + (lane&15)  (MFMA C layout).
// ---------------------------------------------------------------------------
static __device__ __forceinline__ void bias_body(int t,
                                                 const float* __restrict__ w1,
                                                 const float* __restrict__ b1,
                                                 const float* __restrict__ w2,
                                                 const float* __restrict__ b2,
                                                 float* __restrict__ bias2) {
    int h = t >> 12;
    int lane = (t >> 6) & 63;
    int pair = t & 63;
    int g = lane >> 4, c = lane & 15;
    int mt = pair >> 4, nt = (pair >> 2) & 3, r = pair & 3;
    int n = 16 * mt + 4 * g + r;
    int m = 16 * nt + c;

    float d0 = (float)((n >> 3) - (m >> 3));
    float d1 = (float)((n & 7) - (m & 7));
    float r0 = (d0 > 0.f ? 1.f : (d0 < 0.f ? -1.f : 0.f)) * log1pf(fabsf(d0));
    float r1 = (d1 > 0.f ? 1.f : (d1 < 0.f ? -1.f : 0.f)) * log1pf(fabsf(d1));
    float a = 0.f;
    for (int j = 0; j < 256; j++) {
        float hd = fmaf(r0, w1[j], fmaf(r1, w1[256 + j], b1[j]));
        hd = fmaxf(hd, 0.f);
        a = fmaf(hd, w2[j * 3 + h], a);
    }
    bias2[t] = (a + b2[h]) * LOG2E;
}

__global__ __launch_bounds__(256) void bias_kernel(const float* __restrict__ w1,
                                                   const float* __restrict__ b1,
                                                   const float* __restrict__ w2,
                                                   const float* __restrict__ b2,
                                                   float* __restrict__ bias2) {
    bias_body(blockIdx.x * 256 + threadIdx.x, w1, b1, w2, b2, bias2);
}

// ---------------------------------------------------------------------------
// SPLIT KERNEL 1: conv. One wave per (b,h). NO LDS, no barriers.
// q,k loaded directly from global (lane = channel -> 128B coalesced lines),
// QS*log2e scale folded into k at f16 pack time, cyclic conv via fdot2
// (verified r12 math), O written f32 to workspace, coalesced.
// Blocks 0..47 additionally compute the bias table in their tail (absorbed
// into the grid's tail, off the critical path).
// ---------------------------------------------------------------------------
__global__ __launch_bounds__(256, 3) void conv_kernel(const float* __restrict__ qkv,
                                                      float* __restrict__ ows,
                                                      const float* __restrict__ w1,
                                                      const float* __restrict__ b1,
                                                      const float* __restrict__ w2,
                                                      const float* __restrict__ b2,
                                                      float* __restrict__ bias2) {
    const int t = threadIdx.x;
    const int w = t >> 6;
    const int lane = t & 63;
    const int bid = blockIdx.x;
    const int h = bid % 3;
    const int b = (bid / 3) * 4 + w;
    const size_t U = (size_t)bid * 4 + w;

    const float* base = qkv + (size_t)b * (64 * 288) + h * 32;
    const float QS = 0.17677669529663687f * LOG2E;   // 32^-0.5 * log2e
    const int dd = lane & 31, H2 = lane >> 5;

    // ---- k reversed-pairs (scaled), rows rotated by 4*H2 ----
    f16x2 krp[64];
    #pragma unroll
    for (int t8 = 0; t8 < 8; t8++) {
        const int rb = ((t8 + 4 * H2) & 7) * 8;
        float k8[8];
        #pragma unroll
        for (int tx = 0; tx < 8; tx++)
            k8[tx] = base[(rb + tx) * 288 + 96 + dd] * QS;
        #pragma unroll
        for (int i = 0; i < 8; i++)
            krp[t8 * 8 + i] = __builtin_amdgcn_cvt_pkrtz(k8[i], k8[(i - 1) & 7]);
    }

    // ---- q pairs (unscaled; scale lives in k) ----
    f16x2 q2[32];
    #pragma unroll
    for (int u = 0; u < 8; u++)
        #pragma unroll
        for (int j = 0; j < 4; j++) {
            float qa = base[(u * 8 + 2 * j) * 288 + dd];
            float qb = base[(u * 8 + 2 * j + 1) * 288 + dd];
            q2[u * 4 + j] = __builtin_amdgcn_cvt_pkrtz(qa, qb);
        }

    // ---- 8x8 cyclic conv via fdot2, f32 accumulate ----
    float acc[4][8];
    #pragma unroll
    for (int yi = 0; yi < 4; yi++)
        #pragma unroll
        for (int x = 0; x < 8; x++) acc[yi][x] = 0.f;

    #pragma unroll
    for (int u = 0; u < 8; u++)
        #pragma unroll
        for (int yi = 0; yi < 4; yi++) {
            const int s = (yi - u) & 7;
            #pragma unroll
            for (int x = 0; x < 8; x++)
                #pragma unroll
                for (int j = 0; j < 4; j++)
                    acc[yi][x] = __builtin_amdgcn_fdot2(
                        q2[u * 4 + j], krp[s * 8 + ((x - 2 * j) & 7)], acc[yi][x], false);
        }

    // ---- O -> workspace, f32 linear [64][32], coalesced ----
    float* op = ows + U * 2048;
    #pragma unroll
    for (int yi = 0; yi < 4; yi++) {
        const int n = (4 * H2 + yi) * 8;
        #pragma unroll
        for (int x = 0; x < 8; x++)
            op[(n + x) * 32 + dd] = acc[yi][x];
    }

    // ---- bias table tail (blocks 0..47 only) ----
    if (bid < 48)
        bias_body(bid * 256 + t, w1, b1, w2, b2, bias2);
}

// ---------------------------------------------------------------------------
// SPLIT KERNEL 2: attention. One wave per (b,h). LDS only for P redistribute.
// Back half of the verified r12 kernel with O-frags sourced from workspace.
// ---------------------------------------------------------------------------
__global__ __launch_bounds__(256, 3) void attn_split(const float* __restrict__ qkv,
                                                     const float* __restrict__ ows,
                                                     const float* __restrict__ bias2,
                                                     float* __restrict__ out) {
    __shared__ unsigned short Ps4[4][64 * 72];

    const int t = threadIdx.x;
    const int w = t >> 6;
    const int lane = t & 63;
    const int bid = blockIdx.x;
    const int h = bid % 3;
    const int b = (bid / 3) * 4 + w;
    const size_t U = (size_t)bid * 4 + w;
    const int g = lane >> 4, c = lane & 15;

    const float* base = qkv + (size_t)b * (64 * 288) + h * 32;
    const float* opp = ows + U * 2048;

    // ---- A-frags of O (hi/lo bf16) from workspace: row = 16*mt + c ----
    short8v Oh[4], Ol[4];
    #pragma unroll
    for (int mt = 0; mt < 4; mt++) {
        const float* rp = opp + (16 * mt + c) * 32 + 8 * g;
        float4 x0 = *(const float4*)rp;
        float4 x1 = *(const float4*)(rp + 4);
        float xs[8] = {x0.x, x0.y, x0.z, x0.w, x1.x, x1.y, x1.z, x1.w};
        #pragma unroll
        for (int j = 0; j < 8; j++) {
            unsigned short hb = f2bf(xs[j]);
            Oh[mt][j] = (short)hb;
            Ol[mt][j] = (short)f2bf(xs[j] - bf2f(hb));
        }
    }

    // ---- B-frags of V^T (hi/lo) from global ----
    short8v Vh[4], Vl[4];
    #pragma unroll
    for (int nt = 0; nt < 4; nt++) {
        const float* vp = base + (16 * nt + c) * 288 + 192 + 8 * g;
        float4 x0 = *(const float4*)vp;
        float4 x1 = *(const float4*)(vp + 4);
        float xs[8] = {x0.x, x0.y, x0.z, x0.w, x1.x, x1.y, x1.z, x1.w};
        #pragma unroll
        for (int j = 0; j < 8; j++) {
            unsigned short hb = f2bf(xs[j]);
            Vh[nt][j] = (short)hb;
            Vl[nt][j] = (short)f2bf(xs[j] - bf2f(hb));
        }
    }

    // ---- S = O * V^T via MFMA (bias C-init; hh+hl+lh ~= fp32) ----
    const float* bb = bias2 + (size_t)h * 16 * 256 + lane * 4;
    f32x4 S[4][4];
    #pragma unroll
    for (int mt = 0; mt < 4; mt++)
        #pragma unroll
        for (int nt = 0; nt < 4; nt++) {
            f32x4 a = __builtin_bit_cast(f32x4, *(const float4*)(bb + (mt * 4 + nt) * 256));
            a = __builtin_amdgcn_mfma_f32_16x16x32_bf16(Oh[mt], Vh[nt], a, 0, 0, 0);
            a = __builtin_amdgcn_mfma_f32_16x16x32_bf16(Oh[mt], Vl[nt], a, 0, 0, 0);
            a = __builtin_amdgcn_mfma_f32_16x16x32_bf16(Ol[mt], Vh[nt], a, 0, 0, 0);
            S[mt][nt] = a;
        }

    // ---- prefetch V for PV stage ----
    float vb[2][2][8];
    #pragma unroll
    for (int kt = 0; kt < 2; kt++)
        #pragma unroll
        for (int dt = 0; dt < 2; dt++)
            #pragma unroll
            for (int j = 0; j < 8; j++)
                vb[kt][dt][j] = base[(32 * kt + 8 * g + j) * 288 + 192 + 16 * dt + c];

    // ---- softmax (max-subtracted, exp2 domain) ----
    float inv[4][4];
    #pragma unroll
    for (int mt = 0; mt < 4; mt++) {
        #pragma unroll
        for (int r = 0; r < 4; r++) {
            float m0 = fmaxf(fmaxf(S[mt][0][r], S[mt][1][r]), fmaxf(S[mt][2][r], S[mt][3][r]));
            m0 = fmaxf(m0, __shfl_xor(m0, 1, 64));
            m0 = fmaxf(m0, __shfl_xor(m0, 2, 64));
            m0 = fmaxf(m0, __shfl_xor(m0, 4, 64));
            m0 = fmaxf(m0, __shfl_xor(m0, 8, 64));
            float s0 = 0.f;
            #pragma unroll
            for (int nt = 0; nt < 4; nt++) {
                float e = exp2_fast(S[mt][nt][r] - m0);
                S[mt][nt][r] = e;
                s0 += e;
            }
            s0 += __shfl_xor(s0, 1, 64);
            s0 += __shfl_xor(s0, 2, 64);
            s0 += __shfl_xor(s0, 4, 64);
            s0 += __shfl_xor(s0, 8, 64);
            inv[mt][r] = 1.f / s0;
        }
    }

    // ---- P (unnormalized) -> LDS bf16 [64][72] ----
    unsigned short* Ps = Ps4[w];
    #pragma unroll
    for (int mt = 0; mt < 4; mt++)
        #pragma unroll
        for (int nt = 0; nt < 4; nt++)
            #pragma unroll
            for (int r = 0; r < 4; r++)
                Ps[(16 * mt + 4 * g + r) * 72 + 16 * nt + c] = f2bf(S[mt][nt][r]);
    asm volatile("s_waitcnt lgkmcnt(0)" ::: "memory");

    // ---- P A-frags ----
    short8v Pf[4][2];
    #pragma unroll
    for (int mt = 0; mt < 4; mt++)
        #pragma unroll
        for (int kt = 0; kt < 2; kt++)
            Pf[mt][kt] = *(const short8v*)(Ps + (16 * mt + c) * 72 + 32 * kt + 8 * g);

    // ---- V B-frags for PV (single bf16) ----
    short8v Vp[2][2];
    #pragma unroll
    for (int kt = 0; kt < 2; kt++)
        #pragma unroll
        for (int dt = 0; dt < 2; dt++)
            #pragma unroll
            for (int j = 0; j < 8; j++)
                Vp[kt][dt][j] = (short)f2bf(vb[kt][dt][j]);

    // ---- X = P * V via MFMA, normalize, store ----
    float* op = out + (size_t)b * (64 * 96) + h * 32;
    #pragma unroll
    for (int mt = 0; mt < 4; mt++)
        #pragma unroll
        for (int dt = 0; dt < 2; dt++) {
            f32x4 a = {0.f, 0.f, 0.f, 0.f};
            a = __builtin_amdgcn_mfma_f32_16x16x32_bf16(Pf[mt][0], Vp[0][dt], a, 0, 0, 0);
            a = __builtin_amdgcn_mfma_f32_16x16x32_bf16(Pf[mt][1], Vp[1][dt], a, 0, 0, 0);
            #pragma unroll
            for (int r = 0; r < 4; r++)
                op[(16 * mt + 4 * g + r) * 96 + 16 * dt + c] = a[r] * inv[mt][r];
        }
}

// ---------------------------------------------------------------------------
// FALLBACK: verbatim round-12 fused kernel (66.3us, verified) — used only
// if ws_size cannot hold the 50MB O workspace.
// ---------------------------------------------------------------------------
__global__ __launch_bounds__(256, 3) void attn_fused(const float* __restrict__ qkv,
                                                     const float* __restrict__ bias2,
                                                     float* __restrict__ out) {
    __shared__ float smem[4][64 * 36];

    const int t = threadIdx.x;
    const int w = t >> 6;
    const int lane = t & 63;
    const int h = blockIdx.x % 3;
    const int b = (blockIdx.x / 3) * 4 + w;

    float* Qs = smem[w];
    const float* base = qkv + (size_t)b * (64 * 288) + h * 32;
    const float QS = 0.17677669529663687f * LOG2E;

    {
        const int nr = lane >> 3, d0 = (lane & 7) * 4;
        #pragma unroll
        for (int s = 0; s < 8; s++) {
            int n = 8 * s + nr;
            float4 q4 = *(const float4*)(base + n * 288 + d0);
            q4.x *= QS; q4.y *= QS; q4.z *= QS; q4.w *= QS;
            *(float4*)(Qs + n * 36 + d0) = q4;
        }
    }

    const int dd = lane & 31, H2 = lane >> 5;
    f16x2 krp[64];
    #pragma unroll
    for (int t8 = 0; t8 < 8; t8++) {
        const int rb = ((t8 + 4 * H2) & 7) * 8;
        float k8[8];
        #pragma unroll
        for (int tx = 0; tx < 8; tx++)
            k8[tx] = base[(rb + tx) * 288 + 96 + dd];
        #pragma unroll
        for (int i = 0; i < 8; i++)
            krp[t8 * 8 + i] = __builtin_amdgcn_cvt_pkrtz(k8[i], k8[(i - 1) & 7]);
    }

    asm volatile("s_waitcnt lgkmcnt(0)" ::: "memory");

    float acc[4][8];
    #pragma unroll
    for (int yi = 0; yi < 4; yi++)
        #pragma unroll
        for (int x = 0; x < 8; x++) acc[yi][x] = 0.f;

    #pragma unroll
    for (int u = 0; u < 8; u++) {
        f16x2 q2[4];
        #pragma unroll
        for (int j = 0; j < 4; j++) {
            float qa = Qs[(u * 8 + 2 * j) * 36 + dd];
            float qb = Qs[(u * 8 + 2 * j + 1) * 36 + dd];
            q2[j] = __builtin_amdgcn_cvt_pkrtz(qa, qb);
        }
        #pragma unroll
        for (int yi = 0; yi < 4; yi++) {
            const int s = (yi - u) & 7;
            #pragma unroll
            for (int x = 0; x < 8; x++) {
                #pragma unroll
                for (int j = 0; j < 4; j++)
                    acc[yi][x] = __builtin_amdgcn_fdot2(
                        q2[j], krp[s * 8 + ((x - 2 * j) & 7)], acc[yi][x], false);
            }
        }
    }

    #pragma unroll
    for (int yi = 0; yi < 4; yi++) {
        const int n = (4 * H2 + yi) * 8;
        #pragma unroll
        for (int x = 0; x < 8; x++)
            Qs[(n + x) * 36 + dd] = acc[yi][x];
    }
    asm volatile("s_waitcnt lgkmcnt(0)" ::: "memory");

    const int g = lane >> 4, c = lane & 15;

    short8v Oh[4], Ol[4];
    #pragma unroll
    for (int mt = 0; mt < 4; mt++) {
        const float* rp = Qs + (16 * mt + c) * 36 + 8 * g;
        float4 x0 = *(const float4*)rp;
        float4 x1 = *(const float4*)(rp + 4);
        float xs[8] = {x0.x, x0.y, x0.z, x0.w, x1.x, x1.y, x1.z, x1.w};
        #pragma unroll
        for (int j = 0; j < 8; j++) {
            unsigned short hb = f2bf(xs[j]);
            Oh[mt][j] = (short)hb;
            Ol[mt][j] = (short)f2bf(xs[j] - bf2f(hb));
        }
    }

    short8v Vh[4], Vl[4];
    #pragma unroll
    for (int nt = 0; nt < 4; nt++) {
        const float* vp = base + (16 * nt + c) * 288 + 192 + 8 * g;
        float4 x0 = *(const float4*)vp;
        float4 x1 = *(const float4*)(vp + 4);
        float xs[8] = {x0.x, x0.y, x0.z, x0.w, x1.x, x1.y, x1.z, x1.w};
        #pragma unroll
        for (int j = 0; j < 8; j++) {
            unsigned short hb = f2bf(xs[j]);
            Vh[nt][j] = (short)hb;
            Vl[nt][j] = (short)f2bf(xs[j] - bf2f(hb));
        }
    }

    const float* bb = bias2 + (size_t)h * 16 * 256 + lane * 4;
    f32x4 S[4][4];
    #pragma unroll
    for (int mt = 0; mt < 4; mt++)
        #pragma unroll
        for (int nt = 0; nt < 4; nt++) {
            f32x4 a = __builtin_bit_cast(f32x4, *(const float4*)(bb + (mt * 4 + nt) * 256));
            a = __builtin_amdgcn_mfma_f32_16x16x32_bf16(Oh[mt], Vh[nt], a, 0, 0, 0);
            a = __builtin_amdgcn_mfma_f32_16x16x32_bf16(Oh[mt], Vl[nt], a, 0, 0, 0);
            a = __builtin_amdgcn_mfma_f32_16x16x32_bf16(Ol[mt], Vh[nt], a, 0, 0, 0);
            S[mt][nt] = a;
        }

    float vb[2][2][8];
    #pragma unroll
    for (int kt = 0; kt < 2; kt++)
        #pragma unroll
        for (int dt = 0; dt < 2; dt++)
            #pragma unroll
            for (int j = 0; j < 8; j++)
                vb[kt][dt][j] = base[(32 * kt + 8 * g + j) * 288 + 192 + 16 * dt + c];

    float inv[4][4];
    #pragma unroll
    for (int mt = 0; mt < 4; mt++) {
        #pragma unroll
        for (int r = 0; r < 4; r++) {
            float m0 = fmaxf(fmaxf(S[mt][0][r], S[mt][1][r]), fmaxf(S[mt][2][r], S[mt][3][r]));
            m0 = fmaxf(m0, __shfl_xor(m0, 1, 64));
            m0 = fmaxf(m0, __shfl_xor(m0, 2, 64));
            m0 = fmaxf(m0, __shfl_xor(m0, 4, 64));
            m0 = fmaxf(m0, __shfl_xor(m0, 8, 64));
            float s0 = 0.f;
            #pragma unroll
            for (int nt = 0; nt < 4; nt++) {
                float e = exp2_fast(S[mt][nt][r] - m0);
                S[mt][nt][r] = e;
                s0 += e;
            }
            s0 += __shfl_xor(s0, 1, 64);
            s0 += __shfl_xor(s0, 2, 64);
            s0 += __shfl_xor(s0, 4, 64);
            s0 += __shfl_xor(s0, 8, 64);
            inv[mt][r] = 1.f / s0;
        }
    }

    unsigned short* Ps = (unsigned short*)Qs;
    #pragma unroll
    for (int mt = 0; mt < 4; mt++)
        #pragma unroll
        for (int nt = 0; nt < 4; nt++)
            #pragma unroll
            for (int r = 0; r < 4; r++)
                Ps[(16 * mt + 4 * g + r) * 72 + 16 * nt + c] = f2bf(S[mt][nt][r]);
    asm volatile("s_waitcnt lgkmcnt(0)" ::: "memory");

    short8v Pf[4][2];
    #pragma unroll
    for (int mt = 0; mt < 4; mt++)
        #pragma unroll
        for (int kt = 0; kt < 2; kt++)
            Pf[mt][kt] = *(const short8v*)(Ps + (16 * mt + c) * 72 + 32 * kt + 8 * g);

    short8v Vp[2][2];
    #pragma unroll
    for (int kt = 0; kt < 2; kt++)
        #pragma unroll
        for (int dt = 0; dt < 2; dt++)
            #pragma unroll
            for (int j = 0; j < 8; j++)
                Vp[kt][dt][j] = (short)f2bf(vb[kt][dt][j]);

    f32x4 X[4][2];
    #pragma unroll
    for (int mt = 0; mt < 4; mt++)
        #pragma unroll
        for (int dt = 0; dt < 2; dt++) {
            f32x4 a = {0.f, 0.f, 0.f, 0.f};
            a = __builtin_amdgcn_mfma_f32_16x16x32_bf16(Pf[mt][0], Vp[0][dt], a, 0, 0, 0);
            a = __builtin_amdgcn_mfma_f32_16x16x32_bf16(Pf[mt][1], Vp[1][dt], a, 0, 0, 0);
            X[mt][dt] = a;
        }

    float* op = out + (size_t)b * (64 * 96) + h * 32;
    #pragma unroll
    for (int mt = 0; mt < 4; mt++)
        #pragma unroll
        for (int dt = 0; dt < 2; dt++)
            #pragma unroll
            for (int r = 0; r < 4; r++)
                op[(16 * mt + 4 * g + r) * 96 + 16 * dt + c] = X[mt][dt][r] * inv[mt][r];
}

extern "C" void kernel_launch(void* const* d_in, const int* in_sizes, int n_in,
                              void* d_out, int out_size, void* d_ws, size_t ws_size,
                              hipStream_t stream) {
    const float* qkv = (const float*)d_in[0];
    const float* w1  = (const float*)d_in[1];
    const float* b1  = (const float*)d_in[2];
    const float* w2  = (const float*)d_in[3];
    const float* b2  = (const float*)d_in[4];
    float* out = (float*)d_out;
    float* bias2 = (float*)d_ws;                        // 48 KB
    const size_t NEED = 49152 + (size_t)6144 * 2048 * 4; // bias + O workspace

    if (ws_size >= NEED) {
        float* ows = (float*)((char*)d_ws + 49152);
        conv_kernel<<<(B_TOT / 4) * NHEAD, 256, 0, stream>>>(qkv, ows, w1, b1, w2, b2, bias2);
        attn_split<<<(B_TOT / 4) * NHEAD, 256, 0, stream>>>(qkv, ows, bias2, out);
    } else {
        bias_kernel<<<48, 256, 0, stream>>>(w1, b1, w2, b2, bias2);
        attn_fused<<<(B_TOT / 4) * NHEAD, 256, 0, stream>>>(qkv, bias2, out);
    }
}

// Round 16
// 64.951 us; speedup vs baseline: 1.1222x; 1.1222x over previous
//
#include <hip/hip_runtime.h>

#define B_TOT 2048
#define NHEAD 3

typedef __attribute__((ext_vector_type(8))) short short8v;
typedef __attribute__((ext_vector_type(4))) float f32x4;
typedef __attribute__((ext_vector_type(2))) __fp16 f16x2;

#define LOG2E 1.4426950408889634f

static __device__ __forceinline__ unsigned short f2bf(float x) {
    unsigned u = __builtin_bit_cast(unsigned, x);
    u += 0x7FFFu + ((u >> 16) & 1u);
    return (unsigned short)(u >> 16);
}
static __device__ __forceinline__ float bf2f(unsigned short s) {
    unsigned u = ((unsigned)s) << 16;
    return __builtin_bit_cast(float, u);
}
static __device__ __forceinline__ float exp2_fast(float x) {
    float r; asm("v_exp_f32 %0, %1" : "=v"(r) : "v"(x)); return r;
}

// ---------------------------------------------------------------------------
// Bias MLP precompute (verified r7-r12), coalesced C-init layout:
//   bias2[((h*16 + mt*4 + nt) * 64 + lane) * 4 + r], pre-scaled by log2e.
// ---------------------------------------------------------------------------
__global__ __launch_bounds__(256) void bias_kernel(const float* __restrict__ w1,
                                                   const float* __restrict__ b1,
                                                   const float* __restrict__ w2,
                                                   const float* __restrict__ b2,
                                                   float* __restrict__ bias2) {
    int t = blockIdx.x * 256 + threadIdx.x;   // 0..12287
    int h = t >> 12;
    int lane = (t >> 6) & 63;
    int pair = t & 63;
    int g = lane >> 4, c = lane & 15;
    int mt = pair >> 4, nt = (pair >> 2) & 3, r = pair & 3;
    int n = 16 * mt + 4 * g + r;
    int m = 16 * nt + c;

    float d0 = (float)((n >> 3) - (m >> 3));
    float d1 = (float)((n & 7) - (m & 7));
    float r0 = (d0 > 0.f ? 1.f : (d0 < 0.f ? -1.f : 0.f)) * log1pf(fabsf(d0));
    float r1 = (d1 > 0.f ? 1.f : (d1 < 0.f ? -1.f : 0.f)) * log1pf(fabsf(d1));
    float a = 0.f;
    for (int j = 0; j < 256; j++) {
        float hd = fmaf(r0, w1[j], fmaf(r1, w1[256 + j], b1[j]));
        hd = fmaxf(hd, 0.f);
        a = fmaf(hd, w2[j * 3 + h], a);
    }
    bias2[((h * 16 + mt * 4 + nt) * 64 + lane) * 4 + r] = (a + b2[h]) * LOG2E;
}

// ---------------------------------------------------------------------------
// Main kernel = round-12 verified kernel + (1) ones-MFMA rowsum replacing the
// 64 sum-shuffles, (2) s_setprio around MFMA clusters. Round-15's failure was
// rcp_fast inline-asm reading a raw MFMA dest (hazard not modeled for inline
// asm) — fixed here by plain 1.f/sa[r] (compiler-generated, hazard-safe).
// ---------------------------------------------------------------------------
__global__ __launch_bounds__(256, 3) void attn_kernel(const float* __restrict__ qkv,
                                                      const float* __restrict__ bias2,
                                                      float* __restrict__ out) {
    // per-wave 9216B region: q [64][36] f32 -> O [64][36] f32 -> P [64][72] bf16
    __shared__ float smem[4][64 * 36];

    const int t = threadIdx.x;
    const int w = t >> 6;
    const int lane = t & 63;
    const int h = blockIdx.x % 3;
    const int b = (blockIdx.x / 3) * 4 + w;

    float* Qs = smem[w];
    const float* base = qkv + (size_t)b * (64 * 288) + h * 32;
    const float QS = 0.17677669529663687f * LOG2E;   // 32^-0.5 * log2e

    // ---- q -> LDS (scaled), coalesced float4 ----
    {
        const int nr = lane >> 3, d0 = (lane & 7) * 4;
        #pragma unroll
        for (int s = 0; s < 8; s++) {
            int n = 8 * s + nr;
            float4 q4 = *(const float4*)(base + n * 288 + d0);
            q4.x *= QS; q4.y *= QS; q4.z *= QS; q4.w *= QS;
            *(float4*)(Qs + n * 36 + d0) = q4;
        }
    }

    // ---- k reversed-pairs (channel dd), rows rotated by 4*H2:
    // krp[t8][i] = {k[i], k[(i-1)&7]} (f16x2) ----
    const int dd = lane & 31, H2 = lane >> 5;
    f16x2 krp[64];
    #pragma unroll
    for (int t8 = 0; t8 < 8; t8++) {
        const int rb = ((t8 + 4 * H2) & 7) * 8;
        float k8[8];
        #pragma unroll
        for (int tx = 0; tx < 8; tx++)
            k8[tx] = base[(rb + tx) * 288 + 96 + dd];
        #pragma unroll
        for (int i = 0; i < 8; i++)
            krp[t8 * 8 + i] = __builtin_amdgcn_cvt_pkrtz(k8[i], k8[(i - 1) & 7]);
    }

    asm volatile("s_waitcnt lgkmcnt(0)" ::: "memory");

    // ---- stage 1: 8x8 cyclic conv via f16 dot2, f32 accumulate ----
    float acc[4][8];
    #pragma unroll
    for (int yi = 0; yi < 4; yi++)
        #pragma unroll
        for (int x = 0; x < 8; x++) acc[yi][x] = 0.f;

    #pragma unroll
    for (int u = 0; u < 8; u++) {
        f16x2 q2[4];
        #pragma unroll
        for (int j = 0; j < 4; j++) {
            float qa = Qs[(u * 8 + 2 * j) * 36 + dd];
            float qb = Qs[(u * 8 + 2 * j + 1) * 36 + dd];
            q2[j] = __builtin_amdgcn_cvt_pkrtz(qa, qb);
        }
        #pragma unroll
        for (int yi = 0; yi < 4; yi++) {
            const int s = (yi - u) & 7;
            #pragma unroll
            for (int x = 0; x < 8; x++) {
                #pragma unroll
                for (int j = 0; j < 4; j++)
                    acc[yi][x] = __builtin_amdgcn_fdot2(
                        q2[j], krp[s * 8 + ((x - 2 * j) & 7)], acc[yi][x], false);
            }
        }
    }

    // ---- O into same LDS region ----
    #pragma unroll
    for (int yi = 0; yi < 4; yi++) {
        const int n = (4 * H2 + yi) * 8;
        #pragma unroll
        for (int x = 0; x < 8; x++)
            Qs[(n + x) * 36 + dd] = acc[yi][x];
    }
    asm volatile("s_waitcnt lgkmcnt(0)" ::: "memory");

    const int g = lane >> 4, c = lane & 15;

    // ---- A-frags of O (hi/lo bf16): row = 16*mt + c, k-chunk = 8*g ----
    short8v Oh[4], Ol[4];
    #pragma unroll
    for (int mt = 0; mt < 4; mt++) {
        const float* rp = Qs + (16 * mt + c) * 36 + 8 * g;
        float4 x0 = *(const float4*)rp;
        float4 x1 = *(const float4*)(rp + 4);
        float xs[8] = {x0.x, x0.y, x0.z, x0.w, x1.x, x1.y, x1.z, x1.w};
        #pragma unroll
        for (int j = 0; j < 8; j++) {
            unsigned short hb = f2bf(xs[j]);
            Oh[mt][j] = (short)hb;
            Ol[mt][j] = (short)f2bf(xs[j] - bf2f(hb));
        }
    }

    // ---- B-frags of V^T (hi/lo): element V[16*nt + c][8*g + j], from global ----
    short8v Vh[4], Vl[4];
    #pragma unroll
    for (int nt = 0; nt < 4; nt++) {
        const float* vp = base + (16 * nt + c) * 288 + 192 + 8 * g;
        float4 x0 = *(const float4*)vp;
        float4 x1 = *(const float4*)(vp + 4);
        float xs[8] = {x0.x, x0.y, x0.z, x0.w, x1.x, x1.y, x1.z, x1.w};
        #pragma unroll
        for (int j = 0; j < 8; j++) {
            unsigned short hb = f2bf(xs[j]);
            Vh[nt][j] = (short)hb;
            Vl[nt][j] = (short)f2bf(xs[j] - bf2f(hb));
        }
    }

    // ---- S = O * V^T via MFMA (bias C-init; hh+hl+lh ~= fp32) ----
    const float* bb = bias2 + (size_t)h * 16 * 256 + lane * 4;
    f32x4 S[4][4];
    __builtin_amdgcn_s_setprio(1);
    #pragma unroll
    for (int mt = 0; mt < 4; mt++)
        #pragma unroll
        for (int nt = 0; nt < 4; nt++) {
            f32x4 a = __builtin_bit_cast(f32x4, *(const float4*)(bb + (mt * 4 + nt) * 256));
            a = __builtin_amdgcn_mfma_f32_16x16x32_bf16(Oh[mt], Vh[nt], a, 0, 0, 0);
            a = __builtin_amdgcn_mfma_f32_16x16x32_bf16(Oh[mt], Vl[nt], a, 0, 0, 0);
            a = __builtin_amdgcn_mfma_f32_16x16x32_bf16(Ol[mt], Vh[nt], a, 0, 0, 0);
            S[mt][nt] = a;
        }
    __builtin_amdgcn_s_setprio(0);

    // ---- prefetch V for PV stage (raw f32, packed later) ----
    float vb[2][2][8];   // [kt][dt][j] = V[32*kt + 8*g + j][16*dt + c]
    #pragma unroll
    for (int kt = 0; kt < 2; kt++)
        #pragma unroll
        for (int dt = 0; dt < 2; dt++)
            #pragma unroll
            for (int j = 0; j < 8; j++)
                vb[kt][dt][j] = base[(32 * kt + 8 * g + j) * 288 + 192 + 16 * dt + c];

    // ---- softmax: max-subtract (shfl) + exp2; SUM deferred to ones-MFMA ----
    #pragma unroll
    for (int mt = 0; mt < 4; mt++) {
        #pragma unroll
        for (int r = 0; r < 4; r++) {
            float m0 = fmaxf(fmaxf(S[mt][0][r], S[mt][1][r]), fmaxf(S[mt][2][r], S[mt][3][r]));
            m0 = fmaxf(m0, __shfl_xor(m0, 1, 64));
            m0 = fmaxf(m0, __shfl_xor(m0, 2, 64));
            m0 = fmaxf(m0, __shfl_xor(m0, 4, 64));
            m0 = fmaxf(m0, __shfl_xor(m0, 8, 64));
            #pragma unroll
            for (int nt = 0; nt < 4; nt++)
                S[mt][nt][r] = exp2_fast(S[mt][nt][r] - m0);
        }
    }

    // ---- P (unnormalized, <=1) -> LDS bf16 [64][72] (aliases O; O consumed) ----
    unsigned short* Ps = (unsigned short*)Qs;
    #pragma unroll
    for (int mt = 0; mt < 4; mt++)
        #pragma unroll
        for (int nt = 0; nt < 4; nt++)
            #pragma unroll
            for (int r = 0; r < 4; r++)
                Ps[(16 * mt + 4 * g + r) * 72 + 16 * nt + c] = f2bf(S[mt][nt][r]);
    asm volatile("s_waitcnt lgkmcnt(0)" ::: "memory");

    // ---- P A-frags: row = 16*mt + c, k-chunk = 32*kt + 8*g ----
    short8v Pf[4][2];
    #pragma unroll
    for (int mt = 0; mt < 4; mt++)
        #pragma unroll
        for (int kt = 0; kt < 2; kt++)
            Pf[mt][kt] = *(const short8v*)(Ps + (16 * mt + c) * 72 + 32 * kt + 8 * g);

    // ---- V B-frags for PV (single bf16) ----
    short8v Vp[2][2];
    #pragma unroll
    for (int kt = 0; kt < 2; kt++)
        #pragma unroll
        for (int dt = 0; dt < 2; dt++)
            #pragma unroll
            for (int j = 0; j < 8; j++)
                Vp[kt][dt][j] = (short)f2bf(vb[kt][dt][j]);

    // ---- row sums via ones-MFMA; inv via plain division (hazard-safe) ----
    short8v ones;
    #pragma unroll
    for (int j = 0; j < 8; j++) ones[j] = (short)0x3F80;   // bf16 1.0
    f32x4 inv4[4];
    __builtin_amdgcn_s_setprio(1);
    #pragma unroll
    for (int mt = 0; mt < 4; mt++) {
        f32x4 sa = {0.f, 0.f, 0.f, 0.f};
        sa = __builtin_amdgcn_mfma_f32_16x16x32_bf16(Pf[mt][0], ones, sa, 0, 0, 0);
        sa = __builtin_amdgcn_mfma_f32_16x16x32_bf16(Pf[mt][1], ones, sa, 0, 0, 0);
        #pragma unroll
        for (int r = 0; r < 4; r++) inv4[mt][r] = 1.f / sa[r];
    }

    // ---- X = P * V via MFMA ----
    f32x4 X[4][2];
    #pragma unroll
    for (int mt = 0; mt < 4; mt++)
        #pragma unroll
        for (int dt = 0; dt < 2; dt++) {
            f32x4 a = {0.f, 0.f, 0.f, 0.f};
            a = __builtin_amdgcn_mfma_f32_16x16x32_bf16(Pf[mt][0], Vp[0][dt], a, 0, 0, 0);
            a = __builtin_amdgcn_mfma_f32_16x16x32_bf16(Pf[mt][1], Vp[1][dt], a, 0, 0, 0);
            X[mt][dt] = a;
        }
    __builtin_amdgcn_s_setprio(0);

    // ---- normalize + store: out[b][n][h*32 + d] ----
    float* op = out + (size_t)b * (64 * 96) + h * 32;
    #pragma unroll
    for (int mt = 0; mt < 4; mt++)
        #pragma unroll
        for (int dt = 0; dt < 2; dt++)
            #pragma unroll
            for (int r = 0; r < 4; r++)
                op[(16 * mt + 4 * g + r) * 96 + 16 * dt + c] = X[mt][dt][r] * inv4[mt][r];
}

extern "C" void kernel_launch(void* const* d_in, const int* in_sizes, int n_in,
                              void* d_out, int out_size, void* d_ws, size_t ws_size,
                              hipStream_t stream) {
    const float* qkv = (const float*)d_in[0];
    const float* w1  = (const float*)d_in[1];
    const float* b1  = (const float*)d_in[2];
    const float* w2  = (const float*)d_in[3];
    const float* b2  = (const float*)d_in[4];
    float* out = (float*)d_out;
    float* bias2 = (float*)d_ws;   // 48 KB

    bias_kernel<<<48, 256, 0, stream>>>(w1, b1, w2, b2, bias2);
    attn_kernel<<<(B_TOT / 4) * NHEAD, 256, 0, stream>>>(qkv, bias2, out);
}